// Round 1
// baseline (166.032 us; speedup 1.0000x reference)
//
#include <hip/hip_runtime.h>
#include <math.h>

// EdgeEmb: out[e] = LN(GeGLU( concat(emb[s]@W1+b1, emb[d]@W2+b2) @ Wm + bm ))
//
// Factored: h[e] = P[s] + Q[d] + dvec, where
//   P = emb @ (W1 @ Wm[:128,:])   [N,256]
//   Q = emb @ (W2 @ Wm[128:,:])   [N,256]
//   dvec = b1@Wm[:128,:] + b2@Wm[128:,:] + bm
// PQ stored interleaved per node: PQ[n][0:256]=P, PQ[n][256:512]=Q.

#define CH 128

// ---------------- Kernel 1: fold weights -------------------------------
// Ccat[128][512]: cols 0..255 = W1@Wm_top, cols 256..511 = W2@Wm_bot
// dvec[256] = b1@Wm_top + b2@Wm_bot + bm
__global__ __launch_bounds__(256) void prep_kernel(
    const float* __restrict__ W1, const float* __restrict__ b1,
    const float* __restrict__ W2, const float* __restrict__ b2,
    const float* __restrict__ Wm, const float* __restrict__ bm,
    float* __restrict__ Ccat, float* __restrict__ dvec) {
  int bid = blockIdx.x;
  int tid = threadIdx.x;
  if (bid < 256) {
    int idx = bid * 256 + tid;          // 0..65535
    int i = idx >> 9;                   // row of C, 0..127
    int j = idx & 511;                  // col 0..511
    int jc = j & 255;
    const float* wrow = (j < 256) ? (W1 + i * CH) : (W2 + i * CH);
    const float* wm   = (j < 256) ? (Wm + jc) : (Wm + CH * 256 + jc);
    float acc = 0.f;
#pragma unroll 8
    for (int k = 0; k < CH; ++k) acc = fmaf(wrow[k], wm[k * 256], acc);
    Ccat[i * 512 + j] = acc;
  } else if (tid < 256) {
    float acc = bm[tid];
#pragma unroll 8
    for (int k = 0; k < CH; ++k) {
      acc = fmaf(b1[k], Wm[k * 256 + tid], acc);
      acc = fmaf(b2[k], Wm[(CH + k) * 256 + tid], acc);
    }
    dvec[tid] = acc;
  }
}

// ---------------- Kernel 2: node GEMM  PQ = emb @ Ccat -----------------
// M x 128 @ 128 x 512.  BM=64, BN=64, full K in LDS, 4x4 per thread.
__global__ __launch_bounds__(256) void node_gemm(
    const float* __restrict__ A,   // [M,128] emb
    const float* __restrict__ B,   // [128,512] Ccat
    float* __restrict__ C,         // [M,512] PQ
    int M) {
  // As row-major [64][132] (pad 132: keeps 16B alignment, spreads banks)
  __shared__ float As[64 * 132];
  __shared__ float Bs[128 * 64];
  const int tid = threadIdx.x;
  const int row0 = blockIdx.x * 64;
  const int col0 = blockIdx.y * 64;

  for (int i = tid * 4; i < 64 * CH; i += 1024) {
    int r = i >> 7, c = i & 127;
    int rg = row0 + r; if (rg >= M) rg = M - 1;     // clamp; store guarded
    float4 v = *(const float4*)(A + (size_t)rg * CH + c);
    *(float4*)(As + r * 132 + c) = v;
  }
  for (int i = tid * 4; i < CH * 64; i += 1024) {
    int k = i >> 6, n = i & 63;
    float4 v = *(const float4*)(B + k * 512 + col0 + n);
    *(float4*)(Bs + k * 64 + n) = v;
  }
  __syncthreads();

  const int tx = tid & 15, ty = tid >> 4;
  float acc[4][4] = {};
#pragma unroll 4
  for (int k = 0; k < CH; k += 4) {
    float a[4][4];   // [row][kk]
    float b[4][4];   // [kk][col]
#pragma unroll
    for (int i = 0; i < 4; ++i)
      *(float4*)a[i] = *(const float4*)(As + (4 * ty + i) * 132 + k);
#pragma unroll
    for (int kk = 0; kk < 4; ++kk)
      *(float4*)b[kk] = *(const float4*)(Bs + (k + kk) * 64 + 4 * tx);
#pragma unroll
    for (int kk = 0; kk < 4; ++kk)
#pragma unroll
      for (int i = 0; i < 4; ++i)
#pragma unroll
        for (int j = 0; j < 4; ++j)
          acc[i][j] = fmaf(a[i][kk], b[kk][j], acc[i][j]);
  }

#pragma unroll
  for (int i = 0; i < 4; ++i) {
    int row = row0 + 4 * ty + i;
    if (row < M)
      *(float4*)(C + (size_t)row * 512 + col0 + 4 * tx) = *(float4*)acc[i];
  }
}

// ---------------- Kernel 3: per-edge gather + GeGLU + LayerNorm --------
// One wave (64 lanes) per edge; lane handles 2 channels.
__global__ __launch_bounds__(256) void edge_kernel(
    const float* __restrict__ PQ,
    const float* __restrict__ dvec,
    const float* __restrict__ gamma,
    const float* __restrict__ beta,
    const int* __restrict__ eidx,   // [2,E] flat
    float* __restrict__ out,        // [E,128]
    int E) {
  const int wave = threadIdx.x >> 6;
  const int lane = threadIdx.x & 63;
  const int e = blockIdx.x * 4 + wave;
  if (e >= E) return;
  const int s = eidx[e];
  const int d = eidx[E + e];
  const int c = lane * 2;

  const float* Ps = PQ + (size_t)s * 512;        // P part of src row
  const float* Qd = PQ + (size_t)d * 512 + 256;  // Q part of dst row

  float2 px = *(const float2*)(Ps + c);
  float2 pg = *(const float2*)(Ps + CH + c);
  float2 qx = *(const float2*)(Qd + c);
  float2 qg = *(const float2*)(Qd + CH + c);
  float2 dx = *(const float2*)(dvec + c);
  float2 dg = *(const float2*)(dvec + CH + c);

  float x0 = px.x + qx.x + dx.x;
  float x1 = px.y + qx.y + dx.y;
  float g0 = pg.x + qg.x + dg.x;
  float g1 = pg.y + qg.y + dg.y;

  const float inv_sqrt2 = 0.70710678118654752440f;
  float y0 = x0 * (0.5f * g0 * (1.0f + erff(g0 * inv_sqrt2)));
  float y1 = x1 * (0.5f * g1 * (1.0f + erff(g1 * inv_sqrt2)));

  float s1 = y0 + y1;
  float s2 = y0 * y0 + y1 * y1;
#pragma unroll
  for (int off = 32; off; off >>= 1) {
    s1 += __shfl_xor(s1, off, 64);
    s2 += __shfl_xor(s2, off, 64);
  }
  float mu  = s1 * (1.0f / 128.0f);
  float var = s2 * (1.0f / 128.0f) - mu * mu;
  float rstd = rsqrtf(var + 1e-5f);

  float2 gm = *(const float2*)(gamma + c);
  float2 bt = *(const float2*)(beta + c);
  float2 o;
  o.x = (y0 - mu) * rstd * gm.x + bt.x;
  o.y = (y1 - mu) * rstd * gm.y + bt.y;
  *(float2*)(out + (size_t)e * CH + c) = o;
}

// ---------------- launch ------------------------------------------------
extern "C" void kernel_launch(void* const* d_in, const int* in_sizes, int n_in,
                              void* d_out, int out_size, void* d_ws, size_t ws_size,
                              hipStream_t stream) {
  const float* emb   = (const float*)d_in[0];
  const int*   eidx  = (const int*)d_in[1];
  const float* W1    = (const float*)d_in[2];
  const float* b1    = (const float*)d_in[3];
  const float* W2    = (const float*)d_in[4];
  const float* b2    = (const float*)d_in[5];
  const float* Wm    = (const float*)d_in[6];
  const float* bm    = (const float*)d_in[7];
  const float* gamma = (const float*)d_in[8];
  const float* beta  = (const float*)d_in[9];

  const int M = in_sizes[0] / CH;   // 20000 nodes
  const int E = in_sizes[1] / 2;    // 320000 edges

  // Workspace layout: Ccat[128*512] | dvec[256] | PQ[M*512]  (~39.3 MiB)
  float* Ccat = (float*)d_ws;
  float* dvec = Ccat + 128 * 512;
  float* PQ   = dvec + 256;

  prep_kernel<<<257, 256, 0, stream>>>(W1, b1, W2, b2, Wm, bm, Ccat, dvec);

  dim3 g2((M + 63) / 64, 512 / 64);
  node_gemm<<<g2, 256, 0, stream>>>(emb, Ccat, PQ, M);

  edge_kernel<<<(E + 3) / 4, 256, 0, stream>>>(PQ, dvec, gamma, beta, eidx,
                                               (float*)d_out, E);
}

// Round 2
// 138.606 us; speedup vs baseline: 1.1979x; 1.1979x over previous
//
#include <hip/hip_runtime.h>
#include <hip/hip_fp16.h>
#include <math.h>

// EdgeEmb: out[e] = LN(GeGLU( concat(emb[s]@W1+b1, emb[d]@W2+b2) @ Wm + bm ))
//
// Factored: h[e] = P[s] + Q[d] + dvec, where
//   P = emb @ (W1 @ Wm[:128,:])   [N,256]
//   Q = emb @ (W2 @ Wm[128:,:])   [N,256]
//   dvec = b1@Wm[:128,:] + b2@Wm[128:,:] + bm
//
// PQ stored per node as 512 f16: [P-interleaved(256) | Q-interleaved(256)]
// where interleave groups channels as {x_{2l}, x_{2l+1}, g_{2l}, g_{2l+1}}
// so one 8B load per lane per endpoint fetches all 4 values it needs.
// The interleave is produced for free by permuting Ccat's columns in prep.

#define CH 128

__device__ __forceinline__ int permcol(int j2) {  // j2 in [0,256)
  int c = j2 & 127;        // channel within x- or gate-half
  int isg = j2 >> 7;       // 0 = x, 1 = gate
  return ((c >> 1) << 2) | (isg << 1) | (c & 1);
}

// ---------------- Kernel 1: fold weights (store permuted cols) ---------
__global__ __launch_bounds__(256) void prep_kernel(
    const float* __restrict__ W1, const float* __restrict__ b1,
    const float* __restrict__ W2, const float* __restrict__ b2,
    const float* __restrict__ Wm, const float* __restrict__ bm,
    float* __restrict__ Ccat, float* __restrict__ dvec) {
  int bid = blockIdx.x;
  int tid = threadIdx.x;
  if (bid < 256) {
    int idx = bid * 256 + tid;          // 0..65535
    int i = idx >> 9;                   // row of C, 0..127
    int j = idx & 511;                  // logical col 0..511
    int jc = j & 255;
    const float* wrow = (j < 256) ? (W1 + i * CH) : (W2 + i * CH);
    const float* wm   = (j < 256) ? (Wm + jc) : (Wm + CH * 256 + jc);
    float acc = 0.f;
#pragma unroll 8
    for (int k = 0; k < CH; ++k) acc = fmaf(wrow[k], wm[k * 256], acc);
    int scol = (j & 256) | permcol(j & 255);
    Ccat[i * 512 + scol] = acc;
  } else if (tid < 256) {
    float acc = bm[tid];
#pragma unroll 8
    for (int k = 0; k < CH; ++k) {
      acc = fmaf(b1[k], Wm[k * 256 + tid], acc);
      acc = fmaf(b2[k], Wm[(CH + k) * 256 + tid], acc);
    }
    dvec[permcol(tid)] = acc;
  }
}

// ---------------- Kernel 2: node GEMM  PQ = emb @ Ccat (f16 out) -------
// M x 128 @ 128 x 512.  BM=64, BN=64, full K in LDS, 4x4 per thread.
__global__ __launch_bounds__(256) void node_gemm(
    const float* __restrict__ A,   // [M,128] emb
    const float* __restrict__ B,   // [128,512] Ccat (cols pre-permuted)
    __half* __restrict__ C,        // [M,512] PQ f16
    int M) {
  __shared__ float As[64 * 132];   // pad 132: 16B-aligned, spreads banks
  __shared__ float Bs[128 * 64];
  const int tid = threadIdx.x;
  const int row0 = blockIdx.x * 64;
  const int col0 = blockIdx.y * 64;

  for (int i = tid * 4; i < 64 * CH; i += 1024) {
    int r = i >> 7, c = i & 127;
    int rg = row0 + r; if (rg >= M) rg = M - 1;     // clamp; store guarded
    float4 v = *(const float4*)(A + (size_t)rg * CH + c);
    *(float4*)(As + r * 132 + c) = v;
  }
  for (int i = tid * 4; i < CH * 64; i += 1024) {
    int k = i >> 6, n = i & 63;
    float4 v = *(const float4*)(B + k * 512 + col0 + n);
    *(float4*)(Bs + k * 64 + n) = v;
  }
  __syncthreads();

  const int tx = tid & 15, ty = tid >> 4;
  float acc[4][4] = {};
#pragma unroll 4
  for (int k = 0; k < CH; k += 4) {
    float a[4][4];   // [row][kk]
    float b[4][4];   // [kk][col]
#pragma unroll
    for (int i = 0; i < 4; ++i)
      *(float4*)a[i] = *(const float4*)(As + (4 * ty + i) * 132 + k);
#pragma unroll
    for (int kk = 0; kk < 4; ++kk)
      *(float4*)b[kk] = *(const float4*)(Bs + (k + kk) * 64 + 4 * tx);
#pragma unroll
    for (int kk = 0; kk < 4; ++kk)
#pragma unroll
      for (int i = 0; i < 4; ++i)
#pragma unroll
        for (int j = 0; j < 4; ++j)
          acc[i][j] = fmaf(a[i][kk], b[kk][j], acc[i][j]);
  }

#pragma unroll
  for (int i = 0; i < 4; ++i) {
    int row = row0 + 4 * ty + i;
    if (row < M) {
      __half2 h0 = __floats2half2_rn(acc[i][0], acc[i][1]);
      __half2 h1 = __floats2half2_rn(acc[i][2], acc[i][3]);
      uint2 u;
      u.x = *(const unsigned int*)&h0;
      u.y = *(const unsigned int*)&h1;
      *(uint2*)(C + (size_t)row * 512 + col0 + 4 * tx) = u;
    }
  }
}

// ---------------- Kernel 3: per-edge gather + GeGLU + LayerNorm --------
// One wave (64 lanes) per edge; lane handles 2 channels.
__global__ __launch_bounds__(256) void edge_kernel(
    const __half* __restrict__ PQ,   // [M][512] f16, interleaved layout
    const float* __restrict__ dvec,  // [256] f32, permuted
    const float* __restrict__ gamma,
    const float* __restrict__ beta,
    const int* __restrict__ eidx,    // [2,E] flat
    float* __restrict__ out,         // [E,128]
    int E) {
  const int wave = threadIdx.x >> 6;
  const int lane = threadIdx.x & 63;
  const int e = blockIdx.x * 4 + wave;
  if (e >= E) return;
  const int s = eidx[e];
  const int d = eidx[E + e];

  // one 8B gathered load per endpoint: 4 halves {x0,x1,g0,g1}
  uint2 pu = *(const uint2*)(PQ + (size_t)s * 512 + lane * 4);
  uint2 qu = *(const uint2*)(PQ + (size_t)d * 512 + 256 + lane * 4);
  float4 dv = *(const float4*)(dvec + lane * 4);

  float2 p01 = __half22float2(*(const __half2*)&pu.x);  // x0,x1
  float2 p23 = __half22float2(*(const __half2*)&pu.y);  // g0,g1
  float2 q01 = __half22float2(*(const __half2*)&qu.x);
  float2 q23 = __half22float2(*(const __half2*)&qu.y);

  float x0 = p01.x + q01.x + dv.x;
  float x1 = p01.y + q01.y + dv.y;
  float g0 = p23.x + q23.x + dv.z;
  float g1 = p23.y + q23.y + dv.w;

  const float inv_sqrt2 = 0.70710678118654752440f;
  float y0 = x0 * (0.5f * g0 * (1.0f + erff(g0 * inv_sqrt2)));
  float y1 = x1 * (0.5f * g1 * (1.0f + erff(g1 * inv_sqrt2)));

  float s1 = y0 + y1;
  float s2 = y0 * y0 + y1 * y1;
#pragma unroll
  for (int off = 32; off; off >>= 1) {
    s1 += __shfl_xor(s1, off, 64);
    s2 += __shfl_xor(s2, off, 64);
  }
  float mu  = s1 * (1.0f / 128.0f);
  float var = s2 * (1.0f / 128.0f) - mu * mu;
  float rstd = rsqrtf(var + 1e-5f);

  const int c = lane * 2;
  float2 gm = *(const float2*)(gamma + c);
  float2 bt = *(const float2*)(beta + c);
  float2 o;
  o.x = (y0 - mu) * rstd * gm.x + bt.x;
  o.y = (y1 - mu) * rstd * gm.y + bt.y;
  *(float2*)(out + (size_t)e * CH + c) = o;
}

// ---------------- launch ------------------------------------------------
extern "C" void kernel_launch(void* const* d_in, const int* in_sizes, int n_in,
                              void* d_out, int out_size, void* d_ws, size_t ws_size,
                              hipStream_t stream) {
  const float* emb   = (const float*)d_in[0];
  const int*   eidx  = (const int*)d_in[1];
  const float* W1    = (const float*)d_in[2];
  const float* b1    = (const float*)d_in[3];
  const float* W2    = (const float*)d_in[4];
  const float* b2    = (const float*)d_in[5];
  const float* Wm    = (const float*)d_in[6];
  const float* bm    = (const float*)d_in[7];
  const float* gamma = (const float*)d_in[8];
  const float* beta  = (const float*)d_in[9];

  const int M = in_sizes[0] / CH;   // 20000 nodes
  const int E = in_sizes[1] / 2;    // 320000 edges

  // Workspace: Ccat f32[128*512] | dvec f32[256] | PQ f16[M*512] (~20.7 MiB)
  float* Ccat = (float*)d_ws;
  float* dvec = Ccat + 128 * 512;
  __half* PQ  = (__half*)(dvec + 256);

  prep_kernel<<<257, 256, 0, stream>>>(W1, b1, W2, b2, Wm, bm, Ccat, dvec);

  dim3 g2((M + 63) / 64, 512 / 64);
  node_gemm<<<g2, 256, 0, stream>>>(emb, Ccat, PQ, M);

  edge_kernel<<<(E + 3) / 4, 256, 0, stream>>>(PQ, dvec, gamma, beta, eidx,
                                               (float*)d_out, E);
}

// Round 3
// 124.008 us; speedup vs baseline: 1.3389x; 1.1177x over previous
//
#include <hip/hip_runtime.h>
#include <hip/hip_fp16.h>
#include <math.h>

// EdgeEmb: out[e] = LN(GeGLU( concat(emb[s]@W1+b1, emb[d]@W2+b2) @ Wm + bm ))
//
// Factored: h[e] = P[s] + Q[d] + dvec, where
//   P = emb @ (W1 @ Wm[:128,:])   [N,256]
//   Q = emb @ (W2 @ Wm[128:,:])   [N,256]
//   dvec = b1@Wm[:128,:] + b2@Wm[128:,:] + bm
//
// PQ stored per node as 512 f16: [P-interleaved(256) | Q-interleaved(256)]
// interleave groups: {x_{2p}, x_{2p+1}, g_{2p}, g_{2p+1}} per 4-group, so a
// 16B lane load fetches 2 pairs = channels 4hl..4hl+3 (x and gate).
// Edge kernel: 2 edges per wave (32 lanes/edge, 4 ch/lane), tanh-form gelu.

#define CH 128

__device__ __forceinline__ int permcol(int j2) {  // j2 in [0,256)
  int c = j2 & 127;        // channel within x- or gate-half
  int isg = j2 >> 7;       // 0 = x, 1 = gate
  return ((c >> 1) << 2) | (isg << 1) | (c & 1);
}

// ---------------- Kernel 1: fold weights (store permuted cols) ---------
__global__ __launch_bounds__(256) void prep_kernel(
    const float* __restrict__ W1, const float* __restrict__ b1,
    const float* __restrict__ W2, const float* __restrict__ b2,
    const float* __restrict__ Wm, const float* __restrict__ bm,
    float* __restrict__ Ccat, float* __restrict__ dvec) {
  int bid = blockIdx.x;
  int tid = threadIdx.x;
  if (bid < 256) {
    int idx = bid * 256 + tid;          // 0..65535
    int i = idx >> 9;                   // row of C, 0..127
    int j = idx & 511;                  // logical col 0..511
    int jc = j & 255;
    const float* wrow = (j < 256) ? (W1 + i * CH) : (W2 + i * CH);
    const float* wm   = (j < 256) ? (Wm + jc) : (Wm + CH * 256 + jc);
    float acc = 0.f;
#pragma unroll 8
    for (int k = 0; k < CH; ++k) acc = fmaf(wrow[k], wm[k * 256], acc);
    int scol = (j & 256) | permcol(j & 255);
    Ccat[i * 512 + scol] = acc;
  } else if (tid < 256) {
    float acc = bm[tid];
#pragma unroll 8
    for (int k = 0; k < CH; ++k) {
      acc = fmaf(b1[k], Wm[k * 256 + tid], acc);
      acc = fmaf(b2[k], Wm[(CH + k) * 256 + tid], acc);
    }
    dvec[permcol(tid)] = acc;
  }
}

// ---------------- Kernel 2: node GEMM  PQ = emb @ Ccat (f16 out) -------
__global__ __launch_bounds__(256) void node_gemm(
    const float* __restrict__ A,   // [M,128] emb
    const float* __restrict__ B,   // [128,512] Ccat (cols pre-permuted)
    __half* __restrict__ C,        // [M,512] PQ f16
    int M) {
  __shared__ float As[64 * 132];   // pad 132: 16B-aligned, spreads banks
  __shared__ float Bs[128 * 64];
  const int tid = threadIdx.x;
  const int row0 = blockIdx.x * 64;
  const int col0 = blockIdx.y * 64;

  for (int i = tid * 4; i < 64 * CH; i += 1024) {
    int r = i >> 7, c = i & 127;
    int rg = row0 + r; if (rg >= M) rg = M - 1;     // clamp; store guarded
    float4 v = *(const float4*)(A + (size_t)rg * CH + c);
    *(float4*)(As + r * 132 + c) = v;
  }
  for (int i = tid * 4; i < CH * 64; i += 1024) {
    int k = i >> 6, n = i & 63;
    float4 v = *(const float4*)(B + k * 512 + col0 + n);
    *(float4*)(Bs + k * 64 + n) = v;
  }
  __syncthreads();

  const int tx = tid & 15, ty = tid >> 4;
  float acc[4][4] = {};
#pragma unroll 4
  for (int k = 0; k < CH; k += 4) {
    float a[4][4];   // [row][kk]
    float b[4][4];   // [kk][col]
#pragma unroll
    for (int i = 0; i < 4; ++i)
      *(float4*)a[i] = *(const float4*)(As + (4 * ty + i) * 132 + k);
#pragma unroll
    for (int kk = 0; kk < 4; ++kk)
      *(float4*)b[kk] = *(const float4*)(Bs + (k + kk) * 64 + 4 * tx);
#pragma unroll
    for (int kk = 0; kk < 4; ++kk)
#pragma unroll
      for (int i = 0; i < 4; ++i)
#pragma unroll
        for (int j = 0; j < 4; ++j)
          acc[i][j] = fmaf(a[i][kk], b[kk][j], acc[i][j]);
  }

#pragma unroll
  for (int i = 0; i < 4; ++i) {
    int row = row0 + 4 * ty + i;
    if (row < M) {
      __half2 h0 = __floats2half2_rn(acc[i][0], acc[i][1]);
      __half2 h1 = __floats2half2_rn(acc[i][2], acc[i][3]);
      uint2 u;
      u.x = *(const unsigned int*)&h0;
      u.y = *(const unsigned int*)&h1;
      *(uint2*)(C + (size_t)row * 512 + col0 + 4 * tx) = u;
    }
  }
}

// tanh-form gelu (max |dev| from exact ~3e-3): g*u/(1+u), u=exp2(g*(a+b*g^2))
__device__ __forceinline__ float gelu_t(float g) {
  float g2 = g * g;
  float t = g * fmaf(g2, 0.10294515f, 2.3021858f);
  float u = exp2f(t);
  return g * u * __builtin_amdgcn_rcpf(1.0f + u);
}

// ---------------- Kernel 3: per-edge gather + GeGLU + LayerNorm --------
// 2 edges per wave: lanes 0-31 -> edge A, 32-63 -> edge B; 4 channels/lane.
__global__ __launch_bounds__(256) void edge_kernel(
    const __half* __restrict__ PQ,   // [M][512] f16, interleaved layout
    const float* __restrict__ dvec,  // [256] f32, permuted
    const float* __restrict__ gamma,
    const float* __restrict__ beta,
    const int* __restrict__ eidx,    // [2,E] flat
    float* __restrict__ out,         // [E,128]
    int E) {
  const int wave = threadIdx.x >> 6;
  const int lane = threadIdx.x & 63;
  const int hl = lane & 31;
  const int e = blockIdx.x * 8 + wave * 2 + (lane >> 5);
  if (e >= E) return;
  const int s = eidx[e];
  const int d = eidx[E + e];

  // one 16B gathered load per endpoint: 8 halves = {x0,x1,g0,g1,x2,x3,g2,g3}
  const char* pqb = (const char*)PQ;
  uint4 pu = *(const uint4*)(pqb + (size_t)s * 1024 + hl * 16);
  uint4 qu = *(const uint4*)(pqb + (size_t)d * 1024 + 512 + hl * 16);
  float4 dv0 = *(const float4*)(dvec + hl * 8);
  float4 dv1 = *(const float4*)(dvec + hl * 8 + 4);

  float2 px01 = __half22float2(*(const __half2*)&pu.x);
  float2 pg01 = __half22float2(*(const __half2*)&pu.y);
  float2 px23 = __half22float2(*(const __half2*)&pu.z);
  float2 pg23 = __half22float2(*(const __half2*)&pu.w);
  float2 qx01 = __half22float2(*(const __half2*)&qu.x);
  float2 qg01 = __half22float2(*(const __half2*)&qu.y);
  float2 qx23 = __half22float2(*(const __half2*)&qu.z);
  float2 qg23 = __half22float2(*(const __half2*)&qu.w);

  float x0 = px01.x + qx01.x + dv0.x;
  float x1 = px01.y + qx01.y + dv0.y;
  float g0 = pg01.x + qg01.x + dv0.z;
  float g1 = pg01.y + qg01.y + dv0.w;
  float x2 = px23.x + qx23.x + dv1.x;
  float x3 = px23.y + qx23.y + dv1.y;
  float g2 = pg23.x + qg23.x + dv1.z;
  float g3 = pg23.y + qg23.y + dv1.w;

  float y0 = x0 * gelu_t(g0);
  float y1 = x1 * gelu_t(g1);
  float y2 = x2 * gelu_t(g2);
  float y3 = x3 * gelu_t(g3);

  float s1 = (y0 + y1) + (y2 + y3);
  float s2 = fmaf(y0, y0, fmaf(y1, y1, fmaf(y2, y2, y3 * y3)));
#pragma unroll
  for (int off = 16; off; off >>= 1) {   // 5 levels: stays within 32-lane half
    s1 += __shfl_xor(s1, off, 64);
    s2 += __shfl_xor(s2, off, 64);
  }
  float mu  = s1 * (1.0f / 128.0f);
  float var = s2 * (1.0f / 128.0f) - mu * mu;
  float rstd = rsqrtf(var + 1e-5f);

  float4 gm = *(const float4*)(gamma + hl * 4);
  float4 bt = *(const float4*)(beta + hl * 4);
  float4 o;
  o.x = fmaf((y0 - mu) * rstd, gm.x, bt.x);
  o.y = fmaf((y1 - mu) * rstd, gm.y, bt.y);
  o.z = fmaf((y2 - mu) * rstd, gm.z, bt.z);
  o.w = fmaf((y3 - mu) * rstd, gm.w, bt.w);
  *(float4*)(out + (size_t)e * CH + hl * 4) = o;
}

// ---------------- launch ------------------------------------------------
extern "C" void kernel_launch(void* const* d_in, const int* in_sizes, int n_in,
                              void* d_out, int out_size, void* d_ws, size_t ws_size,
                              hipStream_t stream) {
  const float* emb   = (const float*)d_in[0];
  const int*   eidx  = (const int*)d_in[1];
  const float* W1    = (const float*)d_in[2];
  const float* b1    = (const float*)d_in[3];
  const float* W2    = (const float*)d_in[4];
  const float* b2    = (const float*)d_in[5];
  const float* Wm    = (const float*)d_in[6];
  const float* bm    = (const float*)d_in[7];
  const float* gamma = (const float*)d_in[8];
  const float* beta  = (const float*)d_in[9];

  const int M = in_sizes[0] / CH;   // 20000 nodes
  const int E = in_sizes[1] / 2;    // 320000 edges

  // Workspace: Ccat f32[128*512] | dvec f32[256] | PQ f16[M*512] (~20.7 MiB)
  float* Ccat = (float*)d_ws;
  float* dvec = Ccat + 128 * 512;
  __half* PQ  = (__half*)(dvec + 256);

  prep_kernel<<<257, 256, 0, stream>>>(W1, b1, W2, b2, Wm, bm, Ccat, dvec);

  dim3 g2((M + 63) / 64, 512 / 64);
  node_gemm<<<g2, 256, 0, stream>>>(emb, Ccat, PQ, M);

  edge_kernel<<<(E + 7) / 8, 256, 0, stream>>>(PQ, dvec, gamma, beta, eidx,
                                               (float*)d_out, E);
}

// Round 4
// 94.615 us; speedup vs baseline: 1.7548x; 1.3107x over previous
//
#include <hip/hip_runtime.h>
#include <hip/hip_fp16.h>
#include <math.h>

// EdgeEmb: out[e] = LN(GeGLU( concat(emb[s]@W1+b1, emb[d]@W2+b2) @ Wm + bm ))
//
// Factored: h[e] = P[s] + Q[d] + dvec, where
//   P = emb @ (W1 @ Wm[:128,:]),  Q = emb @ (W2 @ Wm[128:,:])   [N,256] each
//   dvec = b1@Wm[:128,:] + b2@Wm[128:,:] + bm
//
// PQ per node: 512 f16 = [P-interleaved(256) | Q-interleaved(256)], interleave
// groups {x_{2p},x_{2p+1},g_{2p},g_{2p+1}} so one 16B lane load = 4 channels.
// Produced by an MFMA GEMM: PQ = emb(f16) @ Ccat(f16), Ccat cols pre-permuted
// and stored TRANSPOSED (CcatT[512][128]) by prep for contiguous B-frags.
// Edge kernel: 2 edges per 32-lane half-wave (MLP), tanh-form gelu, 5-level
// shuffle LayerNorm.

#define CH 128

typedef _Float16 half8 __attribute__((ext_vector_type(8)));
typedef float floatx4 __attribute__((ext_vector_type(4)));

__device__ __forceinline__ int permcol(int j2) {  // j2 in [0,256)
  int c = j2 & 127;        // channel within x- or gate-half
  int isg = j2 >> 7;       // 0 = x, 1 = gate
  return ((c >> 1) << 2) | (isg << 1) | (c & 1);
}

// ---------------- Kernel 1: fold weights -------------------------------
// CcatT f16 [512][128]: CcatT[scol][i] = (W1|W2 @ Wm-half)[i][scol-permuted]
// dvec f32 [256] permuted.
__global__ __launch_bounds__(256) void prep_kernel(
    const float* __restrict__ W1, const float* __restrict__ b1,
    const float* __restrict__ W2, const float* __restrict__ b2,
    const float* __restrict__ Wm, const float* __restrict__ bm,
    __half* __restrict__ CcatT, float* __restrict__ dvec) {
  int bid = blockIdx.x;
  int tid = threadIdx.x;
  if (bid < 256) {
    int idx = bid * 256 + tid;          // 0..65535
    int i = idx >> 9;                   // row of C, 0..127
    int j = idx & 511;                  // logical col 0..511
    int jc = j & 255;
    const float* wrow = (j < 256) ? (W1 + i * CH) : (W2 + i * CH);
    const float* wm   = (j < 256) ? (Wm + jc) : (Wm + CH * 256 + jc);
    float acc = 0.f;
#pragma unroll 8
    for (int k = 0; k < CH; ++k) acc = fmaf(wrow[k], wm[k * 256], acc);
    int scol = (j & 256) | permcol(j & 255);
    CcatT[scol * CH + i] = __float2half(acc);
  } else if (tid < 256) {
    float acc = bm[tid];
#pragma unroll 8
    for (int k = 0; k < CH; ++k) {
      acc = fmaf(b1[k], Wm[k * 256 + tid], acc);
      acc = fmaf(b2[k], Wm[(CH + k) * 256 + tid], acc);
    }
    dvec[permcol(tid)] = acc;
  }
}

// ---------------- Kernel 2: MFMA node GEMM  PQ = emb @ Ccat ------------
// BM=64, BN=64, K=128 in one shot. 4 waves; wave w does rows w*16..w*16+15.
// LDS rows padded to 136 halves (272B = 17 quads) -> conflict-free b128 reads.
__global__ __launch_bounds__(256) void node_gemm(
    const float* __restrict__ A,     // [M,128] emb f32
    const __half* __restrict__ BT,   // [512,128] CcatT f16
    __half* __restrict__ C,          // [M,512] PQ f16
    int M) {
  __shared__ __align__(16) _Float16 As[64 * 136];
  __shared__ __align__(16) _Float16 Bs[64 * 136];
  const int tid = threadIdx.x;
  const int row0 = blockIdx.x * 64;
  const int col0 = blockIdx.y * 64;

#pragma unroll
  for (int rnd = 0; rnd < 4; ++rnd) {
    int idx = (tid + rnd * 256) * 8;         // element index, 8 halves/thread
    int r = idx >> 7, c = idx & 127;
    int rg = row0 + r; if (rg >= M) rg = M - 1;
    float4 v0 = *(const float4*)(A + (size_t)rg * CH + c);
    float4 v1 = *(const float4*)(A + (size_t)rg * CH + c + 4);
    __half2 h0 = __floats2half2_rn(v0.x, v0.y);
    __half2 h1 = __floats2half2_rn(v0.z, v0.w);
    __half2 h2 = __floats2half2_rn(v1.x, v1.y);
    __half2 h3 = __floats2half2_rn(v1.z, v1.w);
    uint4 u;
    u.x = *(const unsigned int*)&h0; u.y = *(const unsigned int*)&h1;
    u.z = *(const unsigned int*)&h2; u.w = *(const unsigned int*)&h3;
    *(uint4*)(As + r * 136 + c) = u;
    uint4 w4 = *(const uint4*)(BT + (size_t)(col0 + r) * CH + c);
    *(uint4*)(Bs + r * 136 + c) = w4;
  }
  __syncthreads();

  const int w = tid >> 6, l = tid & 63;
  const int mr = w * 16 + (l & 15);
  const int kq = (l >> 4) * 8;               // k-offset within 32-chunk

  half8 a[4];
#pragma unroll
  for (int kc = 0; kc < 4; ++kc)
    a[kc] = *(const half8*)(As + mr * 136 + kc * 32 + kq);

  floatx4 acc[4] = {{0,0,0,0},{0,0,0,0},{0,0,0,0},{0,0,0,0}};
#pragma unroll
  for (int kc = 0; kc < 4; ++kc) {
#pragma unroll
    for (int nb = 0; nb < 4; ++nb) {
      half8 b = *(const half8*)(Bs + (nb * 16 + (l & 15)) * 136 + kc * 32 + kq);
      acc[nb] = __builtin_amdgcn_mfma_f32_16x16x32_f16(a[kc], b, acc[nb], 0, 0, 0);
    }
  }

  // D mapping: col = lane&15, row = (lane>>4)*4 + reg   [m89-verified]
  const int colb = col0 + (l & 15);
  const int rowb = row0 + w * 16 + (l >> 4) * 4;
#pragma unroll
  for (int nb = 0; nb < 4; ++nb) {
#pragma unroll
    for (int rg = 0; rg < 4; ++rg) {
      int row = rowb + rg;
      if (row < M)
        C[(size_t)row * 512 + colb + nb * 16] = __float2half(acc[nb][rg]);
    }
  }
}

// tanh-form gelu (max |dev| from exact ~3e-3): g*u/(1+u), u=exp2(g*(a+b*g^2))
__device__ __forceinline__ float gelu_t(float g) {
  float g2 = g * g;
  float t = g * fmaf(g2, 0.10294515f, 2.3021858f);
  float u = exp2f(t);
  return g * u * __builtin_amdgcn_rcpf(1.0f + u);
}

__device__ __forceinline__ void process_edge(
    uint4 pu, uint4 qu, float4 dv0, float4 dv1, float4 gm, float4 bt,
    float* __restrict__ outp, int hl) {
  float2 px01 = __half22float2(*(const __half2*)&pu.x);
  float2 pg01 = __half22float2(*(const __half2*)&pu.y);
  float2 px23 = __half22float2(*(const __half2*)&pu.z);
  float2 pg23 = __half22float2(*(const __half2*)&pu.w);
  float2 qx01 = __half22float2(*(const __half2*)&qu.x);
  float2 qg01 = __half22float2(*(const __half2*)&qu.y);
  float2 qx23 = __half22float2(*(const __half2*)&qu.z);
  float2 qg23 = __half22float2(*(const __half2*)&qu.w);

  float x0 = px01.x + qx01.x + dv0.x;
  float x1 = px01.y + qx01.y + dv0.y;
  float g0 = pg01.x + qg01.x + dv0.z;
  float g1 = pg01.y + qg01.y + dv0.w;
  float x2 = px23.x + qx23.x + dv1.x;
  float x3 = px23.y + qx23.y + dv1.y;
  float g2 = pg23.x + qg23.x + dv1.z;
  float g3 = pg23.y + qg23.y + dv1.w;

  float y0 = x0 * gelu_t(g0);
  float y1 = x1 * gelu_t(g1);
  float y2 = x2 * gelu_t(g2);
  float y3 = x3 * gelu_t(g3);

  float s1 = (y0 + y1) + (y2 + y3);
  float s2 = fmaf(y0, y0, fmaf(y1, y1, fmaf(y2, y2, y3 * y3)));
#pragma unroll
  for (int off = 16; off; off >>= 1) {   // 5 levels: stays within 32-lane half
    s1 += __shfl_xor(s1, off, 64);
    s2 += __shfl_xor(s2, off, 64);
  }
  float mu  = s1 * (1.0f / 128.0f);
  float var = s2 * (1.0f / 128.0f) - mu * mu;
  float rstd = rsqrtf(var + 1e-5f);

  float4 o;
  o.x = fmaf((y0 - mu) * rstd, gm.x, bt.x);
  o.y = fmaf((y1 - mu) * rstd, gm.y, bt.y);
  o.z = fmaf((y2 - mu) * rstd, gm.z, bt.z);
  o.w = fmaf((y3 - mu) * rstd, gm.w, bt.w);
  *(float4*)(outp + hl * 4) = o;
}

// ---------------- Kernel 3: per-edge gather + GeGLU + LayerNorm --------
// 4 edges per wave: each 32-lane half processes edges {base, base+2}.
// All 4 gathers issued before any compute (MLP); invariants hoisted.
__global__ __launch_bounds__(256) void edge_kernel(
    const __half* __restrict__ PQ,   // [M][512] f16, interleaved layout
    const float* __restrict__ dvec,  // [256] f32, permuted
    const float* __restrict__ gamma,
    const float* __restrict__ beta,
    const int* __restrict__ eidx,    // [2,E] flat
    float* __restrict__ out,         // [E,128]
    int E) {
  const int wave = threadIdx.x >> 6;
  const int lane = threadIdx.x & 63;
  const int hl = lane & 31;
  const int side = lane >> 5;
  const int eA = blockIdx.x * 16 + wave * 4 + side;
  const int eB = eA + 2;
  if (eA >= E) return;
  const bool vB = (eB < E);

  float4 dv0 = *(const float4*)(dvec + hl * 8);
  float4 dv1 = *(const float4*)(dvec + hl * 8 + 4);
  float4 gm  = *(const float4*)(gamma + hl * 4);
  float4 bt  = *(const float4*)(beta + hl * 4);

  const int sA = eidx[eA],           dA = eidx[E + eA];
  const int sB = vB ? eidx[eB] : 0,  dB = vB ? eidx[E + eB] : 0;

  const char* pqb = (const char*)PQ;
  uint4 puA = *(const uint4*)(pqb + (size_t)sA * 1024 + hl * 16);
  uint4 quA = *(const uint4*)(pqb + (size_t)dA * 1024 + 512 + hl * 16);
  uint4 puB = *(const uint4*)(pqb + (size_t)sB * 1024 + hl * 16);
  uint4 quB = *(const uint4*)(pqb + (size_t)dB * 1024 + 512 + hl * 16);

  process_edge(puA, quA, dv0, dv1, gm, bt, out + (size_t)eA * CH, hl);
  if (vB)
    process_edge(puB, quB, dv0, dv1, gm, bt, out + (size_t)eB * CH, hl);
}

// ---------------- launch ------------------------------------------------
extern "C" void kernel_launch(void* const* d_in, const int* in_sizes, int n_in,
                              void* d_out, int out_size, void* d_ws, size_t ws_size,
                              hipStream_t stream) {
  const float* emb   = (const float*)d_in[0];
  const int*   eidx  = (const int*)d_in[1];
  const float* W1    = (const float*)d_in[2];
  const float* b1    = (const float*)d_in[3];
  const float* W2    = (const float*)d_in[4];
  const float* b2    = (const float*)d_in[5];
  const float* Wm    = (const float*)d_in[6];
  const float* bm    = (const float*)d_in[7];
  const float* gamma = (const float*)d_in[8];
  const float* beta  = (const float*)d_in[9];

  const int M = in_sizes[0] / CH;   // 20000 nodes
  const int E = in_sizes[1] / 2;    // 320000 edges

  // Workspace: dvec f32[256] | CcatT f16[512*128] | PQ f16[M*512]  (~20.6MiB)
  float*  dvec  = (float*)d_ws;
  __half* CcatT = (__half*)(dvec + 256);
  __half* PQ    = CcatT + 512 * CH;

  prep_kernel<<<257, 256, 0, stream>>>(W1, b1, W2, b2, Wm, bm, CcatT, dvec);

  dim3 g2((M + 63) / 64, 512 / 64);
  node_gemm<<<g2, 256, 0, stream>>>(emb, CcatT, PQ, M);

  edge_kernel<<<(E + 15) / 16, 256, 0, stream>>>(PQ, dvec, gamma, beta, eidx,
                                                 (float*)d_out, E);
}